// Round 1
// 267.363 us; speedup vs baseline: 1.0167x; 1.0167x over previous
//
#include <hip/hip_runtime.h>

// Problem constants: B=2, C=256, P=64 (NH=4, HD=16), H=W=64 -> N=4096, G=16.
#define B_ 2
#define C_ 256
#define P_ 64
#define N_ 4096
#define EPS_ 1e-5f
// SCALE * log2(e): softmax computed in exp2 domain (folded into q)
#define QSCALE_ 0.3606737602222409f

typedef _Float16 half2v __attribute__((ext_vector_type(2)));
typedef _Float16 half4 __attribute__((ext_vector_type(4)));
typedef _Float16 half8 __attribute__((ext_vector_type(8)));
typedef float f32x4 __attribute__((ext_vector_type(4)));
typedef unsigned int uint2v __attribute__((ext_vector_type(2)));

// f16-domain Schraudolph exp2: t = s*1024 + 15360.5 (f32 FMA, exact grid;
// +0.5 -> truncating cvt becomes round-to-nearest on the f16 mantissa grid).
// v_cvt_u32_f32 clamps negative t to 0 (p = +0.0), v_cvt_pk_u16_u32 packs
// two f16 bit patterns into one register. 1.5 VALU ops per element.
static __device__ __forceinline__ unsigned int pkexp2(float t0, float t1) {
  unsigned int pk, tmp;
  asm("v_cvt_u32_f32 %0, %2\n\t"
      "v_cvt_u32_f32 %1, %3\n\t"
      "v_cvt_pk_u16_u32 %0, %0, %1"
      : "=&v"(pk), "=&v"(tmp)
      : "v"(t0), "v"(t1));
  return pk;
}

struct TP {
  const float* feat[3];
  const float* Wq[3]; const float* bq[3];
  const float* Wk[3]; const float* bk[3];
  const float* Wv[3]; const float* bv[3];
  const float* Wo[3]; const float* bo[3];
  const float* gm[3]; const float* bt[3];
  _Float16* q16;   // [3][2][4096][64]  scaled q
  _Float16* k16;   // [3][8(b4h)][4096][16]
  _Float16* v16;   // [3][8][16][4096]
  _Float16* ao0;   // [3][2][4096][64]  unnormalized O, kv-half 0
  _Float16* ao1;   // kv-half 1
  float* L;        // [2][3][8(bh)][4096] softmax partial denominators
  float* stats;    // [3][2][16][2] {sum, sumsq}
  float* out;
  int ctx0[3]; int ctx1[3];
};

// ---------------------------------------------------------------------------
// Fused projection (unchanged): stages 64n x 256c fp32 feat tile ->
// LDS f16 [n][c]; W fragments converted fp32->f16 in registers.
// grid (128, 2, 3): x<64 KV (K=512 both ctx feats), x>=64 Q. block 256.
// ---------------------------------------------------------------------------
#define PST_ 264
#define VTS_ 88

__global__ __launch_bounds__(256) void proj_fused_kernel(TP P) {
  __shared__ _Float16 bs[64 * PST_];
  const int m = blockIdx.z, b = blockIdx.y;
  const int tid = threadIdx.x;
  const int w = tid >> 6, g = (tid >> 4) & 3, t = tid & 15;
  const bool is_q = blockIdx.x >= 64;
  const int n0 = (is_q ? blockIdx.x - 64 : (int)blockIdx.x) * 64;
  const int sn = tid & 63, scb = (tid >> 6) * 16;

  if (is_q) {
    const float* __restrict__ in = P.feat[m] + (size_t)b * C_ * N_ + n0 + sn;
#pragma unroll
    for (int cc = 0; cc < 4; ++cc) {
      const int c0 = cc * 64 + scb;
      float f[16];
#pragma unroll
      for (int i = 0; i < 16; ++i) f[i] = in[(size_t)(c0 + i) * N_];
      half8 h0, h1;
#pragma unroll
      for (int j = 0; j < 8; ++j) { h0[j] = (_Float16)f[j]; h1[j] = (_Float16)f[8 + j]; }
      *(half8*)(bs + sn * PST_ + c0) = h0;
      *(half8*)(bs + sn * PST_ + c0 + 8) = h1;
    }
    __syncthreads();
    f32x4 a[4] = {{0.f,0.f,0.f,0.f},{0.f,0.f,0.f,0.f},{0.f,0.f,0.f,0.f},{0.f,0.f,0.f,0.f}};
    const float* __restrict__ Wq = P.Wq[m] + (w * 16 + t) * 256;
#pragma unroll
    for (int ks = 0; ks < 8; ++ks) {
      const float4 wa = *(const float4*)(Wq + ks * 32 + g * 8);
      const float4 wb = *(const float4*)(Wq + ks * 32 + g * 8 + 4);
      half8 af;
      af[0] = (_Float16)wa.x; af[1] = (_Float16)wa.y;
      af[2] = (_Float16)wa.z; af[3] = (_Float16)wa.w;
      af[4] = (_Float16)wb.x; af[5] = (_Float16)wb.y;
      af[6] = (_Float16)wb.z; af[7] = (_Float16)wb.w;
#pragma unroll
      for (int i = 0; i < 4; ++i) {
        const half8 bf = *(const half8*)(bs + (i * 16 + t) * PST_ + ks * 32 + g * 8);
        a[i] = __builtin_amdgcn_mfma_f32_16x16x32_f16(af, bf, a[i], 0, 0, 0);
      }
    }
    float bq[4];
#pragma unroll
    for (int r = 0; r < 4; ++r) bq[r] = P.bq[m][w * 16 + g * 4 + r];
    _Float16* qo = P.q16 + ((size_t)(m * 2 + b) * N_) * 64 + w * 16 + g * 4;
#pragma unroll
    for (int i = 0; i < 4; ++i) {
      half4 hq;
#pragma unroll
      for (int r = 0; r < 4; ++r) hq[r] = (_Float16)((a[i][r] + bq[r]) * QSCALE_);
      *(half4*)(qo + (size_t)(n0 + i * 16 + t) * 64) = hq;
    }
  } else {
    f32x4 ka[4] = {{0.f,0.f,0.f,0.f},{0.f,0.f,0.f,0.f},{0.f,0.f,0.f,0.f},{0.f,0.f,0.f,0.f}};
    f32x4 va[4] = {{0.f,0.f,0.f,0.f},{0.f,0.f,0.f,0.f},{0.f,0.f,0.f,0.f},{0.f,0.f,0.f,0.f}};
    const int srcs[2] = {P.ctx0[m], P.ctx1[m]};
    for (int src = 0; src < 2; ++src) {
      const float* __restrict__ in =
          P.feat[srcs[src]] + (size_t)b * C_ * N_ + n0 + sn;
      if (src) __syncthreads();
#pragma unroll
      for (int cc = 0; cc < 4; ++cc) {
        const int c0 = cc * 64 + scb;
        float f[16];
#pragma unroll
        for (int i = 0; i < 16; ++i) f[i] = in[(size_t)(c0 + i) * N_];
        half8 h0, h1;
#pragma unroll
        for (int j = 0; j < 8; ++j) { h0[j] = (_Float16)f[j]; h1[j] = (_Float16)f[8 + j]; }
        *(half8*)(bs + sn * PST_ + c0) = h0;
        *(half8*)(bs + sn * PST_ + c0 + 8) = h1;
      }
      __syncthreads();
      const float* __restrict__ Wk = P.Wk[m] + (w * 16 + t) * 512 + src * 256;
      const float* __restrict__ Wv = P.Wv[m] + (w * 16 + t) * 512 + src * 256;
#pragma unroll
      for (int ks = 0; ks < 8; ++ks) {
        const float4 k0 = *(const float4*)(Wk + ks * 32 + g * 8);
        const float4 k1 = *(const float4*)(Wk + ks * 32 + g * 8 + 4);
        const float4 v0 = *(const float4*)(Wv + ks * 32 + g * 8);
        const float4 v1 = *(const float4*)(Wv + ks * 32 + g * 8 + 4);
        half8 ak, av;
        ak[0] = (_Float16)k0.x; ak[1] = (_Float16)k0.y;
        ak[2] = (_Float16)k0.z; ak[3] = (_Float16)k0.w;
        ak[4] = (_Float16)k1.x; ak[5] = (_Float16)k1.y;
        ak[6] = (_Float16)k1.z; ak[7] = (_Float16)k1.w;
        av[0] = (_Float16)v0.x; av[1] = (_Float16)v0.y;
        av[2] = (_Float16)v0.z; av[3] = (_Float16)v0.w;
        av[4] = (_Float16)v1.x; av[5] = (_Float16)v1.y;
        av[6] = (_Float16)v1.z; av[7] = (_Float16)v1.w;
#pragma unroll
        for (int i = 0; i < 4; ++i) {
          const half8 bf = *(const half8*)(bs + (i * 16 + t) * PST_ + ks * 32 + g * 8);
          ka[i] = __builtin_amdgcn_mfma_f32_16x16x32_f16(ak, bf, ka[i], 0, 0, 0);
          va[i] = __builtin_amdgcn_mfma_f32_16x16x32_f16(av, bf, va[i], 0, 0, 0);
        }
      }
    }
    float bk[4], bv[4];
#pragma unroll
    for (int r = 0; r < 4; ++r) {
      bk[r] = P.bk[m][w * 16 + g * 4 + r];
      bv[r] = P.bv[m][w * 16 + g * 4 + r];
    }
    _Float16* ko = P.k16 + ((size_t)(m * 8 + b * 4 + w) * N_) * 16 + g * 4;
#pragma unroll
    for (int i = 0; i < 4; ++i) {
      half4 hk;
#pragma unroll
      for (int r = 0; r < 4; ++r) hk[r] = (_Float16)(ka[i][r] + bk[r]);
      *(half4*)(ko + (size_t)(n0 + i * 16 + t) * 16) = hk;
    }
    __syncthreads();
#pragma unroll
    for (int i = 0; i < 4; ++i)
#pragma unroll
      for (int r = 0; r < 4; ++r)
        bs[(w * 16 + g * 4 + r) * VTS_ + i * 16 + t] = (_Float16)(va[i][r] + bv[r]);
    __syncthreads();
#pragma unroll
    for (int pass = 0; pass < 2; ++pass) {
      const int row = pass * 32 + (tid >> 3);
      const int hh = row >> 4, dd = row & 15, nb = (tid & 7) * 8;
      const half8 hv = *(const half8*)(bs + row * VTS_ + nb);
      *(half8*)(P.v16 + ((size_t)(m * 8 + b * 4 + hh) * 16 + dd) * N_ + n0 + nb) = hv;
    }
  }
}

// ---------------------------------------------------------------------------
// MFMA flash attention, split-kv x2. 512-thread blocks (8 waves, wave = one
// 16-q tile); each block covers 128 q x 2048 kv.
// R10: softmax VALU chain rebuilt — f16-bit Schraudolph via f32 FMA +
// v_cvt_u32 + v_cvt_pk_u16_u32 (p born packed; +0.5 magic keeps the RNE
// f16 grid => numerics unchanged), denominator via v_dot2_f32_f16 against
// (1,1) (f32-exact, half the adds). ~2.5 VALU ops/elem vs ~5-6 before.
// grid (64, 8, 3): x = qb*2 + kv-half.
// ---------------------------------------------------------------------------
#define KST_ 24

__global__ __launch_bounds__(512) void attn_kernel(TP P) {
  const int m = blockIdx.z, bh = blockIdx.y;
  const int tid = threadIdx.x;
  if (m == 0 && bh == 0 && blockIdx.x == 0 && tid < 192) P.stats[tid] = 0.f;
  const int kvh = blockIdx.x & 1, qb = blockIdx.x >> 1;
  const int kvbase = kvh * 2048;
  const int w = tid >> 6, g = (tid >> 4) & 3, t = tid & 15;
  const _Float16* __restrict__ kh = P.k16 + ((size_t)(m * 8 + bh) * N_) * 16;
  const _Float16* __restrict__ vh = P.v16 + ((size_t)(m * 8 + bh) * 16) * N_;
  const int b = bh >> 2, h = bh & 3;
  const _Float16* __restrict__ qh =
      P.q16 + ((size_t)(m * 2 + b) * N_) * 64 + h * 16 + g * 4;

  const int q0 = qb * 128 + w * 16;
  const half4 qf = *(const half4*)(qh + (size_t)(q0 + t) * 64);

  __shared__ _Float16 ks[256 * KST_];  // [kv][d] stride 24 -> floor banks
  __shared__ _Float16 vs[16 * 256];    // [d][kv], XOR-swizzled (floor)

  const int kr = tid >> 1, kc8 = tid & 1;   // K: 256 rows x 2 half8
  const int vr = tid >> 5, vc = tid & 31;   // V: 16 rows x 32 half8
  const _Float16* kgp = kh + (size_t)(kvbase + kr) * 16 + kc8 * 8;
  const _Float16* vgp = vh + (size_t)vr * N_ + kvbase + vc * 8;
  _Float16* ksp = ks + kr * KST_ + kc8 * 8;
  _Float16* vsp = vs + vr * 256 + ((vc ^ vr) << 3);

  half8 kpre = *(const half8*)kgp;
  half8 vpre = *(const half8*)vgp;

  const half2v one2 = {(_Float16)1.0f, (_Float16)1.0f};
  float l0 = 0.f, l1 = 0.f, l2 = 0.f, l3 = 0.f;
  f32x4 O0 = {0.f,0.f,0.f,0.f}, O1 = {0.f,0.f,0.f,0.f};

  for (int c0 = 0; c0 < 2048; c0 += 256) {
    *(half8*)ksp = kpre;
    *(half8*)vsp = vpre;
    __syncthreads();
    const int nxt = (c0 + 256 < 2048) ? c0 + 256 : 0;
    kpre = *(const half8*)(kgp + (size_t)nxt * 16);
    vpre = *(const half8*)(vgp + nxt);
#pragma unroll
    for (int hc = 0; hc < 4; ++hc) {
      f32x4 s[4];
#pragma unroll
      for (int i = 0; i < 4; ++i) {
        const int sub = hc * 4 + i;
        const half4 kf = *(const half4*)(ks + (sub * 16 + t) * KST_ +
                                         (g >> 1) * 8 + (g & 1) * 4);
        const f32x4 z = {0.f, 0.f, 0.f, 0.f};
        s[i] = __builtin_amdgcn_mfma_f32_16x16x16f16(kf, qf, z, 0, 0, 0);
      }
      unsigned int pk0[4], pk1[4];
#pragma unroll
      for (int i = 0; i < 4; ++i) {
        const float t0 = fmaf(s[i][0], 1024.f, 15360.5f);
        const float t1 = fmaf(s[i][1], 1024.f, 15360.5f);
        const float t2 = fmaf(s[i][2], 1024.f, 15360.5f);
        const float t3 = fmaf(s[i][3], 1024.f, 15360.5f);
        pk0[i] = pkexp2(t0, t1);
        pk1[i] = pkexp2(t2, t3);
      }
      l0 = __builtin_amdgcn_fdot2(__builtin_bit_cast(half2v, pk0[0]), one2, l0, false);
      l1 = __builtin_amdgcn_fdot2(__builtin_bit_cast(half2v, pk1[0]), one2, l1, false);
      l2 = __builtin_amdgcn_fdot2(__builtin_bit_cast(half2v, pk0[1]), one2, l2, false);
      l3 = __builtin_amdgcn_fdot2(__builtin_bit_cast(half2v, pk1[1]), one2, l3, false);
      l0 = __builtin_amdgcn_fdot2(__builtin_bit_cast(half2v, pk0[2]), one2, l0, false);
      l1 = __builtin_amdgcn_fdot2(__builtin_bit_cast(half2v, pk1[2]), one2, l1, false);
      l2 = __builtin_amdgcn_fdot2(__builtin_bit_cast(half2v, pk0[3]), one2, l2, false);
      l3 = __builtin_amdgcn_fdot2(__builtin_bit_cast(half2v, pk1[3]), one2, l3, false);
#pragma unroll
      for (int i = 0; i < 4; ++i) {
        uint2v up;
        up[0] = pk0[i];
        up[1] = pk1[i];
        const half4 pf = __builtin_bit_cast(half4, up);
        const int c = (hc * 4 + i) * 2 + (g >> 1);
        const half4 vf = *(const half4*)(vs + t * 256 + ((c ^ t) << 3) + (g & 1) * 4);
        if (i & 1) O1 = __builtin_amdgcn_mfma_f32_16x16x16f16(vf, pf, O1, 0, 0, 0);
        else       O0 = __builtin_amdgcn_mfma_f32_16x16x16f16(vf, pf, O0, 0, 0, 0);
      }
    }
    __syncthreads();
  }
  float l = (l0 + l1) + (l2 + l3);
  l += __shfl_xor(l, 16);
  l += __shfl_xor(l, 32);
  _Float16* aop = (kvh ? P.ao1 : P.ao0) +
                  ((size_t)(m * 2 + b) * N_ + q0 + t) * 64 + h * 16 + g * 4;
  half4 hv;
#pragma unroll
  for (int r = 0; r < 4; ++r) hv[r] = (_Float16)(O0[r] + O1[r]);  // UNNORMALIZED
  *(half4*)aop = hv;
  if (g == 0 && (tid & 48) == 0)
    P.L[((size_t)(kvh * 3 + m) * 8 + bh) * N_ + q0 + t] = l;
}

// ---------------------------------------------------------------------------
// Wo projection + bias + residual -> d_out, fused GroupNorm stats.
// Stages ao0+ao1 (summed) in LDS; per-fragment lane-uniform 1/(l0+l1) scale
// applied pre-MFMA (head = kst*2 + (g>>1) is fragment-uniform).
// grid (64, 8, 3).
// ---------------------------------------------------------------------------
#define BS_ 72

__global__ __launch_bounds__(256) void wo_resid_kernel(TP P) {
  __shared__ _Float16 as[64 * BS_];
  const int m = blockIdx.z;
  const int b = blockIdx.y >> 2, cblk = blockIdx.y & 3;
  const int n0 = blockIdx.x * 64;
  const int tid = threadIdx.x;
  const int w = tid >> 6, g = (tid >> 4) & 3, t = tid & 15;
  const int c0 = cblk * 64 + w * 16;
  const size_t aob = ((size_t)(m * 2 + b) * N_) * 64;
  const _Float16* __restrict__ a0p = P.ao0 + aob;
  const _Float16* __restrict__ a1p = P.ao1 + aob;
  // stage summed ao tile
  const int ar = tid >> 2, ac = (tid & 3) * 16;
  {
    const size_t off = (size_t)(n0 + ar) * 64 + ac;
    half8 s0 = *(const half8*)(a0p + off);
    half8 s1 = *(const half8*)(a0p + off + 8);
    const half8 u0 = *(const half8*)(a1p + off);
    const half8 u1 = *(const half8*)(a1p + off + 8);
#pragma unroll
    for (int r = 0; r < 8; ++r) { s0[r] += u0[r]; s1[r] += u1[r]; }
    *(half8*)(as + ar * BS_ + ac) = s0;
    *(half8*)(as + ar * BS_ + ac + 8) = s1;
  }
  __syncthreads();
  const float* __restrict__ L0 = P.L + ((size_t)m * 8 + b * 4) * N_;
  const float* __restrict__ L1 = P.L + ((size_t)(3 + m) * 8 + b * 4) * N_;
  f32x4 acc[4] = {{0.f,0.f,0.f,0.f},{0.f,0.f,0.f,0.f},{0.f,0.f,0.f,0.f},{0.f,0.f,0.f,0.f}};
  const float* __restrict__ Wo = P.Wo[m] + (c0 + t) * 64;
#pragma unroll
  for (int kst = 0; kst < 2; ++kst) {
    const float4 w0 = *(const float4*)(Wo + kst * 32 + g * 8);
    const float4 w1 = *(const float4*)(Wo + kst * 32 + g * 8 + 4);
    half8 a;
    a[0] = (_Float16)w0.x; a[1] = (_Float16)w0.y;
    a[2] = (_Float16)w0.z; a[3] = (_Float16)w0.w;
    a[4] = (_Float16)w1.x; a[5] = (_Float16)w1.y;
    a[6] = (_Float16)w1.z; a[7] = (_Float16)w1.w;
    const int head = kst * 2 + (g >> 1);
#pragma unroll
    for (int i = 0; i < 4; ++i) {
      const int n = n0 + i * 16 + t;
      half8 bf = *(const half8*)(as + (i * 16 + t) * BS_ + kst * 32 + g * 8);
      const float ls = L0[(size_t)head * N_ + n] + L1[(size_t)head * N_ + n];
      const _Float16 hs = (_Float16)(1.0f / ls);
#pragma unroll
      for (int r = 0; r < 8; ++r) bf[r] *= hs;
      acc[i] = __builtin_amdgcn_mfma_f32_16x16x32_f16(a, bf, acc[i], 0, 0, 0);
    }
  }
  const float* __restrict__ X = P.feat[m] + (size_t)b * C_ * N_;
  float* outb = P.out + (size_t)m * B_ * C_ * N_ + (size_t)b * C_ * N_;
  float s = 0.f, s2 = 0.f;
#pragma unroll
  for (int i = 0; i < 4; ++i) {
    const int n = n0 + i * 16 + t;
#pragma unroll
    for (int r = 0; r < 4; ++r) {
      const int c = c0 + g * 4 + r;
      const float val = acc[i][r] + X[(size_t)c * N_ + n] + P.bo[m][c];
      outb[(size_t)c * N_ + n] = val;
      s += val;
      s2 += val * val;
    }
  }
#pragma unroll
  for (int off = 1; off < 64; off <<= 1) {
    s += __shfl_xor(s, off);
    s2 += __shfl_xor(s2, off);
  }
  if ((tid & 63) == 0) {
    const int group = cblk * 4 + w;
    float* st = P.stats + ((size_t)(m * 2 + b) * 16 + group) * 2;
    atomicAdd(st, s);
    atomicAdd(st + 1, s2);
  }
}

// ---------------------------------------------------------------------------
// GroupNorm normalize pass, 4 float4 per thread. grid (1536), block 256.
// ---------------------------------------------------------------------------
__global__ __launch_bounds__(256) void gn_final_kernel(TP P) {
  const size_t base = ((size_t)blockIdx.x * 256 + threadIdx.x) * 4;
#pragma unroll
  for (int it = 0; it < 4; ++it) {
    const size_t idx = base + (size_t)it * 1572864;
    const int m = (int)(idx >> 21);
    const int rem = (int)(idx & ((1u << 21) - 1));
    const int b = rem >> 20;
    const int c = (rem >> 12) & 255;
    const float* st = P.stats + ((size_t)(m * 2 + b) * 16 + (c >> 4)) * 2;
    const float mean = st[0] * (1.f / 65536.f);
    const float var = st[1] * (1.f / 65536.f) - mean * mean;
    const float rstd = rsqrtf(var + EPS_);
    const float ga = P.gm[m][c] * rstd, be = P.bt[m][c];
    float4 x = *(float4*)(P.out + idx);
    x.x = (x.x - mean) * ga + be;
    x.y = (x.y - mean) * ga + be;
    x.z = (x.z - mean) * ga + be;
    x.w = (x.w - mean) * ga + be;
    *(float4*)(P.out + idx) = x;
  }
}

// ---------------------------------------------------------------------------
extern "C" void kernel_launch(void* const* d_in, const int* in_sizes, int n_in,
                              void* d_out, int out_size, void* d_ws, size_t ws_size,
                              hipStream_t stream) {
  TP P;
  for (int m = 0; m < 3; ++m) {
    P.feat[m] = (const float*)d_in[m];
    const int base = 3 + m * 10;
    P.Wq[m] = (const float*)d_in[base + 0];
    P.bq[m] = (const float*)d_in[base + 1];
    P.Wk[m] = (const float*)d_in[base + 2];
    P.bk[m] = (const float*)d_in[base + 3];
    P.Wv[m] = (const float*)d_in[base + 4];
    P.bv[m] = (const float*)d_in[base + 5];
    P.Wo[m] = (const float*)d_in[base + 6];
    P.bo[m] = (const float*)d_in[base + 7];
    P.gm[m] = (const float*)d_in[base + 8];
    P.bt[m] = (const float*)d_in[base + 9];
  }
  _Float16* ws = (_Float16*)d_ws;
  P.q16 = ws;                        // 1,572,864 halfs
  P.k16 = ws + 1572864;
  P.v16 = ws + 3145728;
  P.ao0 = ws + 4718592;
  P.ao1 = ws + 6291456;
  P.L = (float*)(ws + 7864320);      // 196,608 floats
  P.stats = (float*)(ws + 7864320) + 196608;  // 192 floats
  P.out = (float*)d_out;
  P.ctx0[0] = 1; P.ctx1[0] = 2;
  P.ctx0[1] = 0; P.ctx1[1] = 2;
  P.ctx0[2] = 0; P.ctx1[2] = 1;

  proj_fused_kernel<<<dim3(128, 2, 3), dim3(256), 0, stream>>>(P);
  attn_kernel<<<dim3(64, 8, 3), dim3(512), 0, stream>>>(P);
  wo_resid_kernel<<<dim3(64, 8, 3), dim3(256), 0, stream>>>(P);
  gn_final_kernel<<<dim3(1536), dim3(256), 0, stream>>>(P);
}

// Round 2
// 252.409 us; speedup vs baseline: 1.0770x; 1.0592x over previous
//
#include <hip/hip_runtime.h>

// Problem constants: B=2, C=256, P=64 (NH=4, HD=16), H=W=64 -> N=4096, G=16.
#define B_ 2
#define C_ 256
#define P_ 64
#define N_ 4096
#define EPS_ 1e-5f
// SCALE * log2(e) * 1024: q pre-scaled so QK^T MFMA (C-init 15360.5) directly
// produces the f16-bit Schraudolph argument t = s*1024 + 15360.5.
#define QSCALE1024_ 369.32993046757467f

typedef _Float16 half4 __attribute__((ext_vector_type(4)));
typedef _Float16 half8 __attribute__((ext_vector_type(8)));
typedef float f32x4 __attribute__((ext_vector_type(4)));
typedef float f32x16 __attribute__((ext_vector_type(16)));
typedef unsigned int uint4v __attribute__((ext_vector_type(4)));

// f16-domain Schraudolph exp2 pack: inputs are t = s*1024 + 15360.5 (already
// computed by the MFMA via scaled q + magic C-init). v_cvt_u32_f32 truncates
// (+0.5 -> round-nearest on f16 grid) and clamps negatives to 0;
// v_cvt_pk_u16_u32 packs two f16 bit patterns into one register.
static __device__ __forceinline__ unsigned int pkexp2(float t0, float t1) {
  unsigned int pk, tmp;
  asm("v_cvt_u32_f32 %0, %2\n\t"
      "v_cvt_u32_f32 %1, %3\n\t"
      "v_cvt_pk_u16_u32 %0, %0, %1"
      : "=&v"(pk), "=&v"(tmp)
      : "v"(t0), "v"(t1));
  return pk;
}

struct TP {
  const float* feat[3];
  const float* Wq[3]; const float* bq[3];
  const float* Wk[3]; const float* bk[3];
  const float* Wv[3]; const float* bv[3];
  const float* Wo[3]; const float* bo[3];
  const float* gm[3]; const float* bt[3];
  _Float16* q16;   // [3][2][4096][64]  scaled q (x QSCALE*1024)
  _Float16* k16;   // [3][8(b4h)][4096][16]
  _Float16* v16;   // [3][8][16][4096]
  _Float16* ao0;   // [3][2][4096][64]  unnormalized O, kv-half 0
  _Float16* ao1;   // kv-half 1
  float* L;        // [2][3][8(bh)][4096] softmax partial denominators
  float* stats;    // [3][2][16][2] {sum, sumsq}
  float* out;
  int ctx0[3]; int ctx1[3];
};

// ---------------------------------------------------------------------------
// Fused projection (only q-scale changed): stages 64n x 256c fp32 feat tile ->
// LDS f16 [n][c]; W fragments converted fp32->f16 in registers.
// grid (128, 2, 3): x<64 KV (K=512 both ctx feats), x>=64 Q. block 256.
// ---------------------------------------------------------------------------
#define PST_ 264
#define VTS_ 88

__global__ __launch_bounds__(256) void proj_fused_kernel(TP P) {
  __shared__ _Float16 bs[64 * PST_];
  const int m = blockIdx.z, b = blockIdx.y;
  const int tid = threadIdx.x;
  const int w = tid >> 6, g = (tid >> 4) & 3, t = tid & 15;
  const bool is_q = blockIdx.x >= 64;
  const int n0 = (is_q ? blockIdx.x - 64 : (int)blockIdx.x) * 64;
  const int sn = tid & 63, scb = (tid >> 6) * 16;

  if (is_q) {
    const float* __restrict__ in = P.feat[m] + (size_t)b * C_ * N_ + n0 + sn;
#pragma unroll
    for (int cc = 0; cc < 4; ++cc) {
      const int c0 = cc * 64 + scb;
      float f[16];
#pragma unroll
      for (int i = 0; i < 16; ++i) f[i] = in[(size_t)(c0 + i) * N_];
      half8 h0, h1;
#pragma unroll
      for (int j = 0; j < 8; ++j) { h0[j] = (_Float16)f[j]; h1[j] = (_Float16)f[8 + j]; }
      *(half8*)(bs + sn * PST_ + c0) = h0;
      *(half8*)(bs + sn * PST_ + c0 + 8) = h1;
    }
    __syncthreads();
    f32x4 a[4] = {{0.f,0.f,0.f,0.f},{0.f,0.f,0.f,0.f},{0.f,0.f,0.f,0.f},{0.f,0.f,0.f,0.f}};
    const float* __restrict__ Wq = P.Wq[m] + (w * 16 + t) * 256;
#pragma unroll
    for (int ks = 0; ks < 8; ++ks) {
      const float4 wa = *(const float4*)(Wq + ks * 32 + g * 8);
      const float4 wb = *(const float4*)(Wq + ks * 32 + g * 8 + 4);
      half8 af;
      af[0] = (_Float16)wa.x; af[1] = (_Float16)wa.y;
      af[2] = (_Float16)wa.z; af[3] = (_Float16)wa.w;
      af[4] = (_Float16)wb.x; af[5] = (_Float16)wb.y;
      af[6] = (_Float16)wb.z; af[7] = (_Float16)wb.w;
#pragma unroll
      for (int i = 0; i < 4; ++i) {
        const half8 bf = *(const half8*)(bs + (i * 16 + t) * PST_ + ks * 32 + g * 8);
        a[i] = __builtin_amdgcn_mfma_f32_16x16x32_f16(af, bf, a[i], 0, 0, 0);
      }
    }
    float bq[4];
#pragma unroll
    for (int r = 0; r < 4; ++r) bq[r] = P.bq[m][w * 16 + g * 4 + r];
    _Float16* qo = P.q16 + ((size_t)(m * 2 + b) * N_) * 64 + w * 16 + g * 4;
#pragma unroll
    for (int i = 0; i < 4; ++i) {
      half4 hq;
#pragma unroll
      for (int r = 0; r < 4; ++r) hq[r] = (_Float16)((a[i][r] + bq[r]) * QSCALE1024_);
      *(half4*)(qo + (size_t)(n0 + i * 16 + t) * 64) = hq;
    }
  } else {
    f32x4 ka[4] = {{0.f,0.f,0.f,0.f},{0.f,0.f,0.f,0.f},{0.f,0.f,0.f,0.f},{0.f,0.f,0.f,0.f}};
    f32x4 va[4] = {{0.f,0.f,0.f,0.f},{0.f,0.f,0.f,0.f},{0.f,0.f,0.f,0.f},{0.f,0.f,0.f,0.f}};
    const int srcs[2] = {P.ctx0[m], P.ctx1[m]};
    for (int src = 0; src < 2; ++src) {
      const float* __restrict__ in =
          P.feat[srcs[src]] + (size_t)b * C_ * N_ + n0 + sn;
      if (src) __syncthreads();
#pragma unroll
      for (int cc = 0; cc < 4; ++cc) {
        const int c0 = cc * 64 + scb;
        float f[16];
#pragma unroll
        for (int i = 0; i < 16; ++i) f[i] = in[(size_t)(c0 + i) * N_];
        half8 h0, h1;
#pragma unroll
        for (int j = 0; j < 8; ++j) { h0[j] = (_Float16)f[j]; h1[j] = (_Float16)f[8 + j]; }
        *(half8*)(bs + sn * PST_ + c0) = h0;
        *(half8*)(bs + sn * PST_ + c0 + 8) = h1;
      }
      __syncthreads();
      const float* __restrict__ Wk = P.Wk[m] + (w * 16 + t) * 512 + src * 256;
      const float* __restrict__ Wv = P.Wv[m] + (w * 16 + t) * 512 + src * 256;
#pragma unroll
      for (int ks = 0; ks < 8; ++ks) {
        const float4 k0 = *(const float4*)(Wk + ks * 32 + g * 8);
        const float4 k1 = *(const float4*)(Wk + ks * 32 + g * 8 + 4);
        const float4 v0 = *(const float4*)(Wv + ks * 32 + g * 8);
        const float4 v1 = *(const float4*)(Wv + ks * 32 + g * 8 + 4);
        half8 ak, av;
        ak[0] = (_Float16)k0.x; ak[1] = (_Float16)k0.y;
        ak[2] = (_Float16)k0.z; ak[3] = (_Float16)k0.w;
        ak[4] = (_Float16)k1.x; ak[5] = (_Float16)k1.y;
        ak[6] = (_Float16)k1.z; ak[7] = (_Float16)k1.w;
        av[0] = (_Float16)v0.x; av[1] = (_Float16)v0.y;
        av[2] = (_Float16)v0.z; av[3] = (_Float16)v0.w;
        av[4] = (_Float16)v1.x; av[5] = (_Float16)v1.y;
        av[6] = (_Float16)v1.z; av[7] = (_Float16)v1.w;
#pragma unroll
        for (int i = 0; i < 4; ++i) {
          const half8 bf = *(const half8*)(bs + (i * 16 + t) * PST_ + ks * 32 + g * 8);
          ka[i] = __builtin_amdgcn_mfma_f32_16x16x32_f16(ak, bf, ka[i], 0, 0, 0);
          va[i] = __builtin_amdgcn_mfma_f32_16x16x32_f16(av, bf, va[i], 0, 0, 0);
        }
      }
    }
    float bk[4], bv[4];
#pragma unroll
    for (int r = 0; r < 4; ++r) {
      bk[r] = P.bk[m][w * 16 + g * 4 + r];
      bv[r] = P.bv[m][w * 16 + g * 4 + r];
    }
    _Float16* ko = P.k16 + ((size_t)(m * 8 + b * 4 + w) * N_) * 16 + g * 4;
#pragma unroll
    for (int i = 0; i < 4; ++i) {
      half4 hk;
#pragma unroll
      for (int r = 0; r < 4; ++r) hk[r] = (_Float16)(ka[i][r] + bk[r]);
      *(half4*)(ko + (size_t)(n0 + i * 16 + t) * 16) = hk;
    }
    __syncthreads();
#pragma unroll
    for (int i = 0; i < 4; ++i)
#pragma unroll
      for (int r = 0; r < 4; ++r)
        bs[(w * 16 + g * 4 + r) * VTS_ + i * 16 + t] = (_Float16)(va[i][r] + bv[r]);
    __syncthreads();
#pragma unroll
    for (int pass = 0; pass < 2; ++pass) {
      const int row = pass * 32 + (tid >> 3);
      const int hh = row >> 4, dd = row & 15, nb = (tid & 7) * 8;
      const half8 hv = *(const half8*)(bs + row * VTS_ + nb);
      *(half8*)(P.v16 + ((size_t)(m * 8 + b * 4 + hh) * 16 + dd) * N_ + n0 + nb) = hv;
    }
  }
}

// ---------------------------------------------------------------------------
// R2 attn: full-rate 32x32x16 MFMA flash attention, split-kv x2.
// 8 waves x 32q each = 256 q per block; 2048 kv per block (split half).
// QK^T: mfma_f32_32x32x16_f16(A=K[32kv][16d], B=Q^T[16d][32q], C=15360.5)
//   -> D[kv][q] IS the f16-Schraudolph argument t (q pre-scaled x1024).
// Softmax: pkexp2 pairs (3 VALU / 2 elems). P repacked into the PV A-frag
// via v_permlane32_swap_b32 (2 per 16-kv chunk).
// PV: mfma_f32_32x32x16_f16(A=P[32q][16kv], B=V'[16kv][32cols]); cols 0-15 =
// V rows, col 16 = ones (accumulates softmax denominator l IN the MFMA),
// cols 17-31 unused garbage. Lane n=lane&31: n<16 holds O, n==16 holds l.
// grid (32, 8, 3): x = qb*2 + kv-half.
// ---------------------------------------------------------------------------
#define KST_ 24
#define VST_ 264

__global__ __launch_bounds__(512) void attn_kernel(TP P) {
  const int m = blockIdx.z, bh = blockIdx.y;
  const int tid = threadIdx.x;
  if (m == 0 && bh == 0 && blockIdx.x == 0 && tid < 192) P.stats[tid] = 0.f;
  const int kvh = blockIdx.x & 1, qb = blockIdx.x >> 1;
  const int kvbase = kvh * 2048;
  const int w = tid >> 6;
  const int lane = tid & 63;
  const int n = lane & 31;   // col id: q for QK-D / d for PV-D
  const int hh = lane >> 5;
  const int b = bh >> 2, h = bh & 3;
  const _Float16* __restrict__ kh = P.k16 + ((size_t)(m * 8 + bh) * N_) * 16;
  const _Float16* __restrict__ vh = P.v16 + ((size_t)(m * 8 + bh) * 16) * N_;
  const int q0 = qb * 256 + w * 32;
  const half8 qf = *(const half8*)(P.q16 +
      ((size_t)(m * 2 + b) * N_ + q0 + n) * 64 + h * 16 + hh * 8);

  __shared__ _Float16 ks[256 * KST_];  // [kv][16d] stride 24: bank-floor b128
  __shared__ _Float16 vs[32 * VST_];   // [col][256kv] stride 264: bank-floor

  // ones column (col 16): in-MFMA l accumulation. rows 17-31 read garbage
  // (their D cols are never consumed). Init once, covered by first barrier.
  if (tid < 32) {
    half8 o8;
#pragma unroll
    for (int j = 0; j < 8; ++j) o8[j] = (_Float16)1.0f;
    *(half8*)(vs + 16 * VST_ + tid * 8) = o8;
  }

  const int kr = tid >> 1, kc8 = tid & 1;   // K: 256 rows x 2 half8
  const int vr = tid >> 5, vc = tid & 31;   // V: 16 rows x 32 half8
  const _Float16* kgp = kh + (size_t)(kvbase + kr) * 16 + kc8 * 8;
  const _Float16* vgp = vh + (size_t)vr * N_ + kvbase + vc * 8;
  _Float16* ksp = ks + kr * KST_ + kc8 * 8;
  _Float16* vsp = vs + vr * VST_ + vc * 8;

  half8 kpre = *(const half8*)kgp;
  half8 vpre = *(const half8*)vgp;

  f32x16 Z, Oe, Oo;
#pragma unroll
  for (int r = 0; r < 16; ++r) { Z[r] = 15360.5f; Oe[r] = 0.f; Oo[r] = 0.f; }

  for (int c0 = 0; c0 < 2048; c0 += 256) {
    *(half8*)ksp = kpre;
    *(half8*)vsp = vpre;
    __syncthreads();
    const int nxt = (c0 + 256 < 2048) ? c0 + 256 : 0;
    kpre = *(const half8*)(kgp + (size_t)nxt * 16);
    vpre = *(const half8*)(vgp + nxt);
#pragma unroll
    for (int sub = 0; sub < 8; ++sub) {
      const half8 kf = *(const half8*)(ks + (sub * 32 + n) * KST_ + hh * 8);
      const f32x16 s = __builtin_amdgcn_mfma_f32_32x32x16_f16(kf, qf, Z, 0, 0, 0);
      // lane holds t for q=q0+n, kv rows (r&3)+8*(r>>2)+4*hh + sub*32.
      unsigned int p0 = pkexp2(s[0], s[1]);    // kv {0,1}+4hh
      unsigned int p1 = pkexp2(s[2], s[3]);    // kv {2,3}+4hh
      unsigned int p2 = pkexp2(s[4], s[5]);    // kv {8,9}+4hh
      unsigned int p3 = pkexp2(s[6], s[7]);    // kv {10,11}+4hh
      unsigned int p4 = pkexp2(s[8], s[9]);    // kv {16,17}+4hh
      unsigned int p5 = pkexp2(s[10], s[11]);  // kv {18,19}+4hh
      unsigned int p6 = pkexp2(s[12], s[13]);  // kv {24,25}+4hh
      unsigned int p7 = pkexp2(s[14], s[15]);  // kv {26,27}+4hh
      // Exchange lane<32/lane>=32 halves: after swap, {p0,p1,p2,p3} is the
      // 32x32x16 A-fragment (k = hh*8+j) for kv chunk sub*32+[0,16),
      // {p4,p5,p6,p7} for chunk sub*32+[16,32).
      asm("v_permlane32_swap_b32 %0, %1" : "+v"(p2), "+v"(p0));
      asm("v_permlane32_swap_b32 %0, %1" : "+v"(p3), "+v"(p1));
      asm("v_permlane32_swap_b32 %0, %1" : "+v"(p6), "+v"(p4));
      asm("v_permlane32_swap_b32 %0, %1" : "+v"(p7), "+v"(p5));
      const uint4v ua = {p0, p1, p2, p3};
      const uint4v ub = {p4, p5, p6, p7};
      const half8 ve = *(const half8*)(vs + n * VST_ + sub * 32 + hh * 8);
      const half8 vo = *(const half8*)(vs + n * VST_ + sub * 32 + 16 + hh * 8);
      Oe = __builtin_amdgcn_mfma_f32_32x32x16_f16(
          __builtin_bit_cast(half8, ua), ve, Oe, 0, 0, 0);
      Oo = __builtin_amdgcn_mfma_f32_32x32x16_f16(
          __builtin_bit_cast(half8, ub), vo, Oo, 0, 0, 0);
    }
    __syncthreads();
  }

  // Epilogue: lane n<16 holds O[q(reg),d=n]; lane n==16 holds l[q(reg)].
  if (n < 16) {
    _Float16* aop = (kvh ? P.ao1 : P.ao0) +
                    ((size_t)(m * 2 + b) * N_ + q0) * 64 + h * 16 + n;
#pragma unroll
    for (int r = 0; r < 16; ++r) {
      const int qrow = (r & 3) + 8 * (r >> 2) + 4 * hh;
      aop[(size_t)qrow * 64] = (_Float16)(Oe[r] + Oo[r]);  // UNNORMALIZED
    }
  } else if (n == 16) {
    float* Lp = P.L + ((size_t)(kvh * 3 + m) * 8 + bh) * N_ + q0;
#pragma unroll
    for (int r = 0; r < 16; ++r) {
      const int qrow = (r & 3) + 8 * (r >> 2) + 4 * hh;
      Lp[qrow] = Oe[r] + Oo[r];
    }
  }
}

// ---------------------------------------------------------------------------
// Wo projection + bias + residual -> d_out, fused GroupNorm stats.
// Stages ao0+ao1 (summed) in LDS; per-fragment lane-uniform 1/(l0+l1) scale
// applied pre-MFMA (head = kst*2 + (g>>1) is fragment-uniform).
// grid (64, 8, 3).
// ---------------------------------------------------------------------------
#define BS_ 72

__global__ __launch_bounds__(256) void wo_resid_kernel(TP P) {
  __shared__ _Float16 as[64 * BS_];
  const int m = blockIdx.z;
  const int b = blockIdx.y >> 2, cblk = blockIdx.y & 3;
  const int n0 = blockIdx.x * 64;
  const int tid = threadIdx.x;
  const int w = tid >> 6, g = (tid >> 4) & 3, t = tid & 15;
  const int c0 = cblk * 64 + w * 16;
  const size_t aob = ((size_t)(m * 2 + b) * N_) * 64;
  const _Float16* __restrict__ a0p = P.ao0 + aob;
  const _Float16* __restrict__ a1p = P.ao1 + aob;
  // stage summed ao tile
  const int ar = tid >> 2, ac = (tid & 3) * 16;
  {
    const size_t off = (size_t)(n0 + ar) * 64 + ac;
    half8 s0 = *(const half8*)(a0p + off);
    half8 s1 = *(const half8*)(a0p + off + 8);
    const half8 u0 = *(const half8*)(a1p + off);
    const half8 u1 = *(const half8*)(a1p + off + 8);
#pragma unroll
    for (int r = 0; r < 8; ++r) { s0[r] += u0[r]; s1[r] += u1[r]; }
    *(half8*)(as + ar * BS_ + ac) = s0;
    *(half8*)(as + ar * BS_ + ac + 8) = s1;
  }
  __syncthreads();
  const float* __restrict__ L0 = P.L + ((size_t)m * 8 + b * 4) * N_;
  const float* __restrict__ L1 = P.L + ((size_t)(3 + m) * 8 + b * 4) * N_;
  f32x4 acc[4] = {{0.f,0.f,0.f,0.f},{0.f,0.f,0.f,0.f},{0.f,0.f,0.f,0.f},{0.f,0.f,0.f,0.f}};
  const float* __restrict__ Wo = P.Wo[m] + (c0 + t) * 64;
#pragma unroll
  for (int kst = 0; kst < 2; ++kst) {
    const float4 w0 = *(const float4*)(Wo + kst * 32 + g * 8);
    const float4 w1 = *(const float4*)(Wo + kst * 32 + g * 8 + 4);
    half8 a;
    a[0] = (_Float16)w0.x; a[1] = (_Float16)w0.y;
    a[2] = (_Float16)w0.z; a[3] = (_Float16)w0.w;
    a[4] = (_Float16)w1.x; a[5] = (_Float16)w1.y;
    a[6] = (_Float16)w1.z; a[7] = (_Float16)w1.w;
    const int head = kst * 2 + (g >> 1);
#pragma unroll
    for (int i = 0; i < 4; ++i) {
      const int nn = n0 + i * 16 + t;
      half8 bf = *(const half8*)(as + (i * 16 + t) * BS_ + kst * 32 + g * 8);
      const float ls = L0[(size_t)head * N_ + nn] + L1[(size_t)head * N_ + nn];
      const _Float16 hs = (_Float16)(1.0f / ls);
#pragma unroll
      for (int r = 0; r < 8; ++r) bf[r] *= hs;
      acc[i] = __builtin_amdgcn_mfma_f32_16x16x32_f16(a, bf, acc[i], 0, 0, 0);
    }
  }
  const float* __restrict__ X = P.feat[m] + (size_t)b * C_ * N_;
  float* outb = P.out + (size_t)m * B_ * C_ * N_ + (size_t)b * C_ * N_;
  float s = 0.f, s2 = 0.f;
#pragma unroll
  for (int i = 0; i < 4; ++i) {
    const int nn = n0 + i * 16 + t;
#pragma unroll
    for (int r = 0; r < 4; ++r) {
      const int c = c0 + g * 4 + r;
      const float val = acc[i][r] + X[(size_t)c * N_ + nn] + P.bo[m][c];
      outb[(size_t)c * N_ + nn] = val;
      s += val;
      s2 += val * val;
    }
  }
#pragma unroll
  for (int off = 1; off < 64; off <<= 1) {
    s += __shfl_xor(s, off);
    s2 += __shfl_xor(s2, off);
  }
  if ((tid & 63) == 0) {
    const int group = cblk * 4 + w;
    float* st = P.stats + ((size_t)(m * 2 + b) * 16 + group) * 2;
    atomicAdd(st, s);
    atomicAdd(st + 1, s2);
  }
}

// ---------------------------------------------------------------------------
// GroupNorm normalize pass, 4 float4 per thread. grid (1536), block 256.
// ---------------------------------------------------------------------------
__global__ __launch_bounds__(256) void gn_final_kernel(TP P) {
  const size_t base = ((size_t)blockIdx.x * 256 + threadIdx.x) * 4;
#pragma unroll
  for (int it = 0; it < 4; ++it) {
    const size_t idx = base + (size_t)it * 1572864;
    const int m = (int)(idx >> 21);
    const int rem = (int)(idx & ((1u << 21) - 1));
    const int b = rem >> 20;
    const int c = (rem >> 12) & 255;
    const float* st = P.stats + ((size_t)(m * 2 + b) * 16 + (c >> 4)) * 2;
    const float mean = st[0] * (1.f / 65536.f);
    const float var = st[1] * (1.f / 65536.f) - mean * mean;
    const float rstd = rsqrtf(var + EPS_);
    const float ga = P.gm[m][c] * rstd, be = P.bt[m][c];
    float4 x = *(float4*)(P.out + idx);
    x.x = (x.x - mean) * ga + be;
    x.y = (x.y - mean) * ga + be;
    x.z = (x.z - mean) * ga + be;
    x.w = (x.w - mean) * ga + be;
    *(float4*)(P.out + idx) = x;
  }
}

// ---------------------------------------------------------------------------
extern "C" void kernel_launch(void* const* d_in, const int* in_sizes, int n_in,
                              void* d_out, int out_size, void* d_ws, size_t ws_size,
                              hipStream_t stream) {
  TP P;
  for (int m = 0; m < 3; ++m) {
    P.feat[m] = (const float*)d_in[m];
    const int base = 3 + m * 10;
    P.Wq[m] = (const float*)d_in[base + 0];
    P.bq[m] = (const float*)d_in[base + 1];
    P.Wk[m] = (const float*)d_in[base + 2];
    P.bk[m] = (const float*)d_in[base + 3];
    P.Wv[m] = (const float*)d_in[base + 4];
    P.bv[m] = (const float*)d_in[base + 5];
    P.Wo[m] = (const float*)d_in[base + 6];
    P.bo[m] = (const float*)d_in[base + 7];
    P.gm[m] = (const float*)d_in[base + 8];
    P.bt[m] = (const float*)d_in[base + 9];
  }
  _Float16* ws = (_Float16*)d_ws;
  P.q16 = ws;                        // 1,572,864 halfs
  P.k16 = ws + 1572864;
  P.v16 = ws + 3145728;
  P.ao0 = ws + 4718592;
  P.ao1 = ws + 6291456;
  P.L = (float*)(ws + 7864320);      // 196,608 floats
  P.stats = (float*)(ws + 7864320) + 196608;  // 192 floats
  P.out = (float*)d_out;
  P.ctx0[0] = 1; P.ctx1[0] = 2;
  P.ctx0[1] = 0; P.ctx1[1] = 2;
  P.ctx0[2] = 0; P.ctx1[2] = 1;

  proj_fused_kernel<<<dim3(128, 2, 3), dim3(256), 0, stream>>>(P);
  attn_kernel<<<dim3(32, 8, 3), dim3(512), 0, stream>>>(P);
  wo_resid_kernel<<<dim3(64, 8, 3), dim3(256), 0, stream>>>(P);
  gn_final_kernel<<<dim3(1536), dim3(256), 0, stream>>>(P);
}